// Round 9
// baseline (1081.872 us; speedup 1.0000x reference)
//
#include <hip/hip_runtime.h>
#include <hip/hip_bf16.h>
#include <stdint.h>

// GRU sequence decoder, fused. B=32768, H=L=512, VOCAB=10, SEQ=6.
// R9: 32x32x16 MFMA. 2x FLOP per operand byte vs 16x16x32: per wave-step
// ds_read_b128 256->128, MFMA instr 768->384, VALU ~halved. Occupancy lever
// abandoned (R7/R8: 2nd 8-wave block never resident); design for 1 block/CU,
// 2 waves/SIMD, 256-reg budget (__launch_bounds__(512,1)), acc[3][2]=96 AGPR.
// Layout notes:
//  - k-position labeling is operand-symmetric: A-pack and B-read use the same
//    position->k map (kk*16 + (lane>>5)*8 + i), so k-order is correctness-free.
//  - C/D (m74/m101-verified): col = lane&31, row = (q&3)+8*(q>>2)+4*(lane>>5).
//    f32x4 group grp=q>>2 covers 4 consecutive j at jt*32 + grp*8 + hi*4.
//  - A row = lane&31 (j), B col = lane&31 (batch).
// Structure from R6 (best, 600us): 8 waves, wave owns 2 jt32 x 2 bt32 x 3 gates;
// h in LDS (XOR swizzle byte^=(row&7)<<4); gi in ws per-lane frag order;
// h_new streamed via hst (global, L2); weights pre-packed to frag order.

typedef __bf16 bf16_t;
typedef bf16_t bf16x8 __attribute__((ext_vector_type(8)));
typedef bf16_t bf16x4 __attribute__((ext_vector_type(4)));
typedef float  f32x4  __attribute__((ext_vector_type(4)));
typedef float  f32x16 __attribute__((ext_vector_type(16)));

#define THREADS 512
#define BM      64
#define NBLK    512
#define NSTEP   6

// ws layout (bytes)
#define WIH_OFF 0u            // 48 nt * 32 kk * 64 lane * 16B = 1572864
#define WHH_OFF 1572864u
#define WOP_OFF 3145728u      // 32 kk * 64 lane * 16B = 32768
#define GI_OFF  4194304u      // 512 blk * 24576 chunks * 8B = 100663296
#define HST_OFF 104857600u    // 512 blk * 128 chunks * 512B = 33554432

static __device__ __forceinline__ float sigm(float v) { return 1.0f / (1.0f + __expf(-v)); }
static __device__ __forceinline__ float tanhf_(float v) {
  v = fminf(fmaxf(v, -12.0f), 12.0f);
  float e = __expf(2.0f * v);
  return 1.0f - 2.0f / (e + 1.0f);
}
static __device__ __forceinline__ f32x4 up4(bf16x4 v) {
  f32x4 o; o[0] = (float)v[0]; o[1] = (float)v[1]; o[2] = (float)v[2]; o[3] = (float)v[3];
  return o;
}
static __device__ __forceinline__ bf16x4 pk4(f32x4 v) {
  bf16x4 o; o[0] = (bf16_t)v[0]; o[1] = (bf16_t)v[1]; o[2] = (bf16_t)v[2]; o[3] = (bf16_t)v[3];
  return o;
}

// Pack weights into 32x32x16 A-frag order:
//   chunk[nt*32 + kk][lane] = w[nt*32 + (lane&31)][kk*16 + (lane>>5)*8 .. +8]
// nt = g*16 + jt (0..47): row = nt*32 + l31 == g*512 + jt*32 + l31. wop: 32 kk
// chunks, rows = vocab (pad 10->32 with zeros).
__global__ void prep_kernel(const float* __restrict__ wih_f, const float* __restrict__ whh_f,
                            const float* __restrict__ wout_f,
                            bf16x8* __restrict__ wihPk, bf16x8* __restrict__ whhPk,
                            bf16x8* __restrict__ wopPk) {
  int c = blockIdx.x * 256 + threadIdx.x;
  int lane = c & 63, l31 = lane & 31, hi = (lane >> 5) & 1;
  if (c < 196608) {
    int cid = (c < 98304) ? c : c - 98304;
    const float* src = (c < 98304) ? wih_f : whh_f;
    bf16x8* dst = (c < 98304) ? wihPk : whhPk;
    int chunk = cid >> 6;                 // 0..1535
    int kk = chunk & 31;
    int nt = chunk >> 5;                  // 0..47
    const float* p = src + (size_t)(nt * 32 + l31) * 512 + kk * 16 + hi * 8;
    bf16x8 o;
    #pragma unroll
    for (int i = 0; i < 8; ++i) o[i] = (bf16_t)p[i];
    dst[chunk * 64 + lane] = o;
  } else if (c < 198656) {
    int chunk = (c - 196608) >> 6;        // kk 0..31
    bf16x8 o;
    if (l31 < 10) {
      const float* p = wout_f + (size_t)l31 * 512 + chunk * 16 + hi * 8;
      #pragma unroll
      for (int i = 0; i < 8; ++i) o[i] = (bf16_t)p[i];
    } else {
      #pragma unroll
      for (int i = 0; i < 8; ++i) o[i] = (bf16_t)0.0f;
    }
    wopPk[chunk * 64 + lane] = o;
  }
}

__global__ __launch_bounds__(THREADS, 1) void gru_kernel(
    const float* __restrict__ x, const float* __restrict__ b_ih,
    const float* __restrict__ b_hh, const float* __restrict__ b_out,
    const bf16x8* __restrict__ wih, const bf16x8* __restrict__ whh,
    const bf16x8* __restrict__ wop,
    bf16x4* __restrict__ gi, bf16x4* __restrict__ hst, float* __restrict__ out) {
  // h tile: 64 rows x 512 bf16, row = 1024B; logical col-byte L of row r at
  // physical L ^ ((r&7)<<4).
  __shared__ __align__(16) char hlds[BM * 1024];

  const int tid   = (int)threadIdx.x;
  const int lane  = tid & 63;
  const int wq    = tid >> 6;      // 0..7: wave owns jt32 in {wq*2, wq*2+1}
  const int l31   = lane & 31;
  const int hi    = lane >> 5;     // k-group / row-group select
  const int brow0 = (int)blockIdx.x * BM;
  const int rswz  = (l31 & 7) << 4;          // row&7 == l31&7 for row=bt*32+l31
  const int kcol  = hi * 16;                 // B-frag byte col base (^ kk*32)

  // ---------------- phase 0: x -> bf16 -> hlds (h0 = x) ----------------
  #pragma unroll
  for (int it = 0; it < 16; ++it) {
    int f4  = it * THREADS + tid;
    int row = f4 >> 7, c4 = f4 & 127;
    float4 v = ((const float4*)(x + (size_t)(brow0 + row) * 512))[c4];
    bf16x4 h4 = { (bf16_t)v.x, (bf16_t)v.y, (bf16_t)v.z, (bf16_t)v.w };
    *(bf16x4*)(&hlds[row * 1024 + ((c4 * 8) ^ ((row & 7) << 4))]) = h4;
  }
  __syncthreads();

  const size_t gibase = (size_t)blockIdx.x * 24576;  // bf16x4 chunks per block
  // gi chunk: (((jt*3 + g)*2 + bt)*4 + grp)*64 + lane,  jt = wq*2 + p (0..15)
  const size_t hstbase = (size_t)blockIdx.x * 8192;
  // hst chunk: ((jt*2 + bt)*4 + grp)*64 + lane

  // ---------------- gi phase: gi = x @ w_ih^T + biases ----------------
  #pragma unroll
  for (int p = 0; p < 2; ++p) {
    const int jt = wq * 2 + p;
    f32x16 aR[2], aZ[2], aN[2];
    #pragma unroll
    for (int bt = 0; bt < 2; ++bt) {
      aR[bt] = (f32x16)(0.0f); aZ[bt] = (f32x16)(0.0f); aN[bt] = (f32x16)(0.0f);
    }
    #pragma unroll 2
    for (int kk = 0; kk < 32; ++kk) {
      bf16x8 wfR = wih[((0 * 512) + jt * 32 + kk) * 64 + lane];
      bf16x8 wfZ = wih[((1 * 512) + jt * 32 + kk) * 64 + lane];
      bf16x8 wfN = wih[((2 * 512) + jt * 32 + kk) * 64 + lane];
      bf16x8 hf0 = *(const bf16x8*)(&hlds[(0 * 32 + l31) * 1024 + ((kk * 32 + kcol) ^ rswz)]);
      bf16x8 hf1 = *(const bf16x8*)(&hlds[(1 * 32 + l31) * 1024 + ((kk * 32 + kcol) ^ rswz)]);
      aR[0] = __builtin_amdgcn_mfma_f32_32x32x16_bf16(wfR, hf0, aR[0], 0, 0, 0);
      aR[1] = __builtin_amdgcn_mfma_f32_32x32x16_bf16(wfR, hf1, aR[1], 0, 0, 0);
      aZ[0] = __builtin_amdgcn_mfma_f32_32x32x16_bf16(wfZ, hf0, aZ[0], 0, 0, 0);
      aZ[1] = __builtin_amdgcn_mfma_f32_32x32x16_bf16(wfZ, hf1, aZ[1], 0, 0, 0);
      aN[0] = __builtin_amdgcn_mfma_f32_32x32x16_bf16(wfN, hf0, aN[0], 0, 0, 0);
      aN[1] = __builtin_amdgcn_mfma_f32_32x32x16_bf16(wfN, hf1, aN[1], 0, 0, 0);
    }
    #pragma unroll
    for (int bt = 0; bt < 2; ++bt)
      #pragma unroll
      for (int grp = 0; grp < 4; ++grp) {
        int j0 = jt * 32 + grp * 8 + hi * 4;      // 4 consecutive j per group
        f32x4 bR = *(const f32x4*)(b_ih + j0) + *(const f32x4*)(b_hh + j0);
        f32x4 bZ = *(const f32x4*)(b_ih + 512 + j0) + *(const f32x4*)(b_hh + 512 + j0);
        f32x4 bN = *(const f32x4*)(b_ih + 1024 + j0);  // b_hh_n stays separate
        f32x4 vR, vZ, vN;
        #pragma unroll
        for (int i = 0; i < 4; ++i) {
          vR[i] = aR[bt][grp * 4 + i] + bR[i];
          vZ[i] = aZ[bt][grp * 4 + i] + bZ[i];
          vN[i] = aN[bt][grp * 4 + i] + bN[i];
        }
        int cb = ((jt * 3) * 2 + bt) * 4 + grp;
        gi[gibase + ((size_t)(cb + 0) << 6) + lane] = pk4(vR);
        gi[gibase + ((size_t)(cb + 8) << 6) + lane] = pk4(vZ);
        gi[gibase + ((size_t)(cb + 16) << 6) + lane] = pk4(vN);
      }
  }
  // (no barrier: hlds unchanged; gi is same-lane RAW, HW-ordered)

  // ---------------- 6 recurrent steps ----------------
  for (int t = 0; t < NSTEP; ++t) {
    #pragma unroll
    for (int p = 0; p < 2; ++p) {
      const int jt = wq * 2 + p;
      f32x16 aR[2], aZ[2], aN[2];
      #pragma unroll
      for (int bt = 0; bt < 2; ++bt) {
        aR[bt] = (f32x16)(0.0f); aZ[bt] = (f32x16)(0.0f); aN[bt] = (f32x16)(0.0f);
      }
      #pragma unroll 2
      for (int kk = 0; kk < 32; ++kk) {
        bf16x8 wfR = whh[((0 * 512) + jt * 32 + kk) * 64 + lane];
        bf16x8 wfZ = whh[((1 * 512) + jt * 32 + kk) * 64 + lane];
        bf16x8 wfN = whh[((2 * 512) + jt * 32 + kk) * 64 + lane];
        bf16x8 hf0 = *(const bf16x8*)(&hlds[(0 * 32 + l31) * 1024 + ((kk * 32 + kcol) ^ rswz)]);
        bf16x8 hf1 = *(const bf16x8*)(&hlds[(1 * 32 + l31) * 1024 + ((kk * 32 + kcol) ^ rswz)]);
        aR[0] = __builtin_amdgcn_mfma_f32_32x32x16_bf16(wfR, hf0, aR[0], 0, 0, 0);
        aR[1] = __builtin_amdgcn_mfma_f32_32x32x16_bf16(wfR, hf1, aR[1], 0, 0, 0);
        aZ[0] = __builtin_amdgcn_mfma_f32_32x32x16_bf16(wfZ, hf0, aZ[0], 0, 0, 0);
        aZ[1] = __builtin_amdgcn_mfma_f32_32x32x16_bf16(wfZ, hf1, aZ[1], 0, 0, 0);
        aN[0] = __builtin_amdgcn_mfma_f32_32x32x16_bf16(wfN, hf0, aN[0], 0, 0, 0);
        aN[1] = __builtin_amdgcn_mfma_f32_32x32x16_bf16(wfN, hf1, aN[1], 0, 0, 0);
      }
      // GRU cell epilogue
      #pragma unroll
      for (int bt = 0; bt < 2; ++bt)
        #pragma unroll
        for (int grp = 0; grp < 4; ++grp) {
          int cb = ((jt * 3) * 2 + bt) * 4 + grp;
          int j0 = jt * 32 + grp * 8 + hi * 4;
          f32x4 gr  = up4(gi[gibase + ((size_t)(cb + 0) << 6) + lane]);
          f32x4 gz  = up4(gi[gibase + ((size_t)(cb + 8) << 6) + lane]);
          f32x4 gn  = up4(gi[gibase + ((size_t)(cb + 16) << 6) + lane]);
          f32x4 bn4 = *(const f32x4*)(b_hh + 1024 + j0);
          f32x4 hov = up4(*(const bf16x4*)(&hlds[(bt * 32 + l31) * 1024 +
                                                 ((jt * 64 + grp * 16 + hi * 8) ^ rswz)]));
          f32x4 hv;
          #pragma unroll
          for (int i = 0; i < 4; ++i) {
            int q = grp * 4 + i;
            float rv = sigm(gr[i] + aR[bt][q]);
            float zv = sigm(gz[i] + aZ[bt][q]);
            float nv = tanhf_(gn[i] + rv * (aN[bt][q] + bn4[i]));
            hv[i] = (1.0f - zv) * nv + zv * hov[i];
          }
          hst[hstbase + ((size_t)((jt * 2 + bt) * 4 + grp) << 6) + lane] = pk4(hv);
        }
    }
    __syncthreads();   // all waves done reading h_t; hst stores drained (vmcnt)

    // copy-back: reload own chunks from hst (L2-hit, coalesced), ds_write hlds
    #pragma unroll
    for (int p = 0; p < 2; ++p) {
      const int jt = wq * 2 + p;
      #pragma unroll
      for (int bt = 0; bt < 2; ++bt)
        #pragma unroll
        for (int grp = 0; grp < 4; ++grp) {
          bf16x4 v = hst[hstbase + ((size_t)((jt * 2 + bt) * 4 + grp) << 6) + lane];
          *(bf16x4*)(&hlds[(bt * 32 + l31) * 1024 +
                           ((jt * 64 + grp * 16 + hi * 8) ^ rswz)]) = v;
        }
    }
    __syncthreads();   // h_{t+1} visible

    // logits_t = h_{t+1} @ w_out^T + b_out ; waves 0,1 own bt32 = wq
    if (wq < 2) {
      f32x16 lacc = (f32x16)(0.0f);
      #pragma unroll 2
      for (int kk = 0; kk < 32; ++kk) {
        bf16x8 hf = *(const bf16x8*)(&hlds[(wq * 32 + l31) * 1024 + ((kk * 32 + kcol) ^ rswz)]);
        bf16x8 wf = wop[kk * 64 + lane];
        lacc = __builtin_amdgcn_mfma_f32_32x32x16_bf16(wf, hf, lacc, 0, 0, 0);
      }
      size_t base = (size_t)(brow0 + wq * 32 + l31) * 60 + t * 10;
      if (hi == 0) {
        // rows v = q (q 0..3) and v = 8 + (q&3) for q 4,5
        f32x4 v0 = { lacc[0] + b_out[0], lacc[1] + b_out[1],
                     lacc[2] + b_out[2], lacc[3] + b_out[3] };
        *(f32x4*)(out + base) = v0;
        out[base + 8] = lacc[4] + b_out[8];
        out[base + 9] = lacc[5] + b_out[9];
      } else {
        // rows v = 4 + q (q 0..3)
        f32x4 v1 = { lacc[0] + b_out[4], lacc[1] + b_out[5],
                     lacc[2] + b_out[6], lacc[3] + b_out[7] };
        *(f32x4*)(out + base + 4) = v1;
      }
    }
  }
}

extern "C" void kernel_launch(void* const* d_in, const int* in_sizes, int n_in,
                              void* d_out, int out_size, void* d_ws, size_t ws_size,
                              hipStream_t stream) {
  const float* x     = (const float*)d_in[0];
  const float* wih_f = (const float*)d_in[1];
  const float* whh_f = (const float*)d_in[2];
  const float* b_ih  = (const float*)d_in[3];
  const float* b_hh  = (const float*)d_in[4];
  const float* wout  = (const float*)d_in[5];
  const float* b_out = (const float*)d_in[6];

  char* ws = (char*)d_ws;
  bf16x8* wihPk = (bf16x8*)(ws + WIH_OFF);
  bf16x8* whhPk = (bf16x8*)(ws + WHH_OFF);
  bf16x8* wopPk = (bf16x8*)(ws + WOP_OFF);
  bf16x4* gi    = (bf16x4*)(ws + GI_OFF);
  bf16x4* hst   = (bf16x4*)(ws + HST_OFF);

  prep_kernel<<<776, 256, 0, stream>>>(wih_f, whh_f, wout, wihPk, whhPk, wopPk);
  gru_kernel<<<NBLK, THREADS, 0, stream>>>(x, b_ih, b_hh, b_out,
                                           wihPk, whhPk, wopPk, gi, hst, (float*)d_out);
}

// Round 10
// 572.676 us; speedup vs baseline: 1.8892x; 1.8892x over previous
//
#include <hip/hip_runtime.h>
#include <hip/hip_bf16.h>
#include <stdint.h>

// GRU sequence decoder, fused. B=32768, H=L=512, VOCAB=10, SEQ=6.
// R10: back to R6 (best, 600us), minus its latency exposures.
//  - h DOUBLE-BUFFERED in LDS (2x64KB=128KB): epilogue ds_writes h_new into
//    buf^1 directly; hst global round-trip deleted; ONE barrier per step.
//  - gi prefetched into regs at pass head (24 VGPR), consumed in epilogue.
//  - __launch_bounds__(512,1): 256-reg cap (2 waves/SIMD by design; R7/R8
//    proved a 2nd 8-wave block never co-resides, so stop paying for it).
//  - kk unroll 4: deeper weight-load pipeline under the 256-reg cap.
// Unchanged from R6: 8 waves, wave owns jtiles [wq*4,wq*4+4) x all 4 btiles;
// A=weight frag (M=j), B=h frag (N=batch); weights pre-packed frag-order
// (L2-resident); gi in ws per-lane frag order (same-lane RAW); XOR swizzle
// byte ^= (row&7)<<4.

typedef __bf16 bf16_t;
typedef bf16_t bf16x8 __attribute__((ext_vector_type(8)));
typedef bf16_t bf16x4 __attribute__((ext_vector_type(4)));
typedef float  f32x4  __attribute__((ext_vector_type(4)));
typedef float  f32x2  __attribute__((ext_vector_type(2)));

#define THREADS 512
#define BM      64
#define NBLK    512
#define NSTEP   6

// ws layout (bytes)
#define WIH_OFF 0u            // 96 nt * 16 kk * 64 lane * 16B = 1572864
#define WHH_OFF 1572864u
#define WOP_OFF 3145728u      // 16 kk * 64 lane * 16B = 16384
#define GI_OFF  4194304u      // 512 blk * 24576 chunks * 8B = 100663296

static __device__ __forceinline__ float sigm(float v) { return 1.0f / (1.0f + __expf(-v)); }
static __device__ __forceinline__ float tanhf_(float v) {
  v = fminf(fmaxf(v, -12.0f), 12.0f);
  float e = __expf(2.0f * v);
  return 1.0f - 2.0f / (e + 1.0f);
}
static __device__ __forceinline__ f32x4 up4(bf16x4 v) {
  f32x4 o; o[0] = (float)v[0]; o[1] = (float)v[1]; o[2] = (float)v[2]; o[3] = (float)v[3];
  return o;
}
static __device__ __forceinline__ bf16x4 pk4(f32x4 v) {
  bf16x4 o; o[0] = (bf16_t)v[0]; o[1] = (bf16_t)v[1]; o[2] = (bf16_t)v[2]; o[3] = (bf16_t)v[3];
  return o;
}

// Pack weights into MFMA A-frag order:
//   chunk[(nt*16 + kk)*64 + lane] = w[nt*16 + (lane&15)][kk*32 + (lane>>4)*8 .. +8]
__global__ void prep_kernel(const float* __restrict__ wih_f, const float* __restrict__ whh_f,
                            const float* __restrict__ wout_f,
                            bf16x8* __restrict__ wihPk, bf16x8* __restrict__ whhPk,
                            bf16x8* __restrict__ wopPk) {
  int c = blockIdx.x * 256 + threadIdx.x;
  int lane = c & 63, l15 = lane & 15, lk = (lane >> 4) & 3;
  if (c < 196608) {
    int cid = (c < 98304) ? c : c - 98304;
    const float* src = (c < 98304) ? wih_f : whh_f;
    bf16x8* dst = (c < 98304) ? wihPk : whhPk;
    int kk = (cid >> 6) & 15;
    int nt = cid >> 10;
    const float* p = src + (size_t)(nt * 16 + l15) * 512 + kk * 32 + lk * 8;
    bf16x8 o;
    #pragma unroll
    for (int i = 0; i < 8; ++i) o[i] = (bf16_t)p[i];
    dst[cid] = o;
  } else if (c < 197632) {
    int cid = c - 196608;          // vocab tile: 16 kk * 64 lane
    int kk = cid >> 6;
    bf16x8 o;
    if (l15 < 10) {
      const float* p = wout_f + (size_t)l15 * 512 + kk * 32 + lk * 8;
      #pragma unroll
      for (int i = 0; i < 8; ++i) o[i] = (bf16_t)p[i];
    } else {
      #pragma unroll
      for (int i = 0; i < 8; ++i) o[i] = (bf16_t)0.0f;
    }
    wopPk[cid] = o;
  }
}

__global__ __launch_bounds__(THREADS, 1) void gru_kernel(
    const float* __restrict__ x, const float* __restrict__ b_ih,
    const float* __restrict__ b_hh, const float* __restrict__ b_out,
    const bf16x8* __restrict__ wih, const bf16x8* __restrict__ whh,
    const bf16x8* __restrict__ wop,
    bf16x4* __restrict__ gi, float* __restrict__ out) {
  // Two h tiles: 64 rows x 512 bf16 each (row = 1024B); logical col-byte L of
  // row r stored at physical L ^ ((r&7)<<4). Step t reads buf[t&1], writes
  // buf[(t+1)&1] -> one barrier per step, no WAR.
  __shared__ __align__(16) char hlds[2 * BM * 1024];

  const int tid   = (int)threadIdx.x;
  const int lane  = tid & 63;
  const int wq    = tid >> 6;      // 0..7: wave owns jtiles [wq*4, wq*4+4)
  const int l15   = lane & 15;
  const int lk    = lane >> 4;
  const int brow0 = (int)blockIdx.x * BM;
  const int swz   = (l15 & 7) << 4;
  const int kbase = (lk * 16) ^ swz;        // b128 read col base (XOR with kk*64)
  const int cbase = (lk * 8) ^ swz;         // b64 cell col base (XOR with jt*32)

  char* cur = hlds;             // h_t
  char* nxt = hlds + BM * 1024; // h_{t+1}

  // ---------------- phase 0: x -> bf16 -> cur (h0 = x) ----------------
  #pragma unroll
  for (int it = 0; it < 16; ++it) {
    int f4  = it * THREADS + tid;
    int row = f4 >> 7, c4 = f4 & 127;
    float4 v = ((const float4*)(x + (size_t)(brow0 + row) * 512))[c4];
    bf16x4 h4 = { (bf16_t)v.x, (bf16_t)v.y, (bf16_t)v.z, (bf16_t)v.w };
    *(bf16x4*)(&cur[row * 1024 + ((c4 * 8) ^ ((row & 7) << 4))]) = h4;
  }
  __syncthreads();

  const size_t gibase = (size_t)blockIdx.x * 24576;  // bf16x4 chunks per block
  // gi chunk: (jt*12 + g*4 + bt)*64 + lane,  jt = wq*4 + p

  // ---------------- gi phase: gi = x @ w_ih^T + biases ----------------
  #pragma unroll
  for (int p = 0; p < 4; ++p) {
    const int jt = wq * 4 + p;
    f32x4 acc[3][4];
    #pragma unroll
    for (int g = 0; g < 3; ++g)
      #pragma unroll
      for (int bt = 0; bt < 4; ++bt) acc[g][bt] = (f32x4){0.f, 0.f, 0.f, 0.f};

    #pragma unroll 4
    for (int kk = 0; kk < 16; ++kk) {
      bf16x8 hf[4];
      #pragma unroll
      for (int bt = 0; bt < 4; ++bt)
        hf[bt] = *(const bf16x8*)(&cur[(bt * 16 + l15) * 1024 + ((kk * 64) ^ kbase)]);
      #pragma unroll
      for (int g = 0; g < 3; ++g) {
        bf16x8 wf = wih[((g * 32 + jt) * 16 + kk) * 64 + lane];
        #pragma unroll
        for (int bt = 0; bt < 4; ++bt)
          acc[g][bt] = __builtin_amdgcn_mfma_f32_16x16x32_bf16(wf, hf[bt], acc[g][bt], 0, 0, 0);
      }
    }
    {
      int j = jt * 16 + lk * 4;
      f32x4 b0 = *(const f32x4*)(b_ih + j) + *(const f32x4*)(b_hh + j);
      f32x4 b1 = *(const f32x4*)(b_ih + 512 + j) + *(const f32x4*)(b_hh + 512 + j);
      f32x4 b2 = *(const f32x4*)(b_ih + 1024 + j);   // b_hh_n stays separate (x r)
      #pragma unroll
      for (int bt = 0; bt < 4; ++bt) {
        int cb = jt * 12 + bt;
        gi[gibase + ((size_t)(cb + 0) << 6) + lane] = pk4(acc[0][bt] + b0);
        gi[gibase + ((size_t)(cb + 4) << 6) + lane] = pk4(acc[1][bt] + b1);
        gi[gibase + ((size_t)(cb + 8) << 6) + lane] = pk4(acc[2][bt] + b2);
      }
    }
  }
  // (no barrier: cur unchanged; gi is same-lane RAW, HW-ordered)

  // ---------------- 6 recurrent steps (one barrier each) ----------------
  for (int t = 0; t < NSTEP; ++t) {
    #pragma unroll
    for (int p = 0; p < 4; ++p) {
      const int jt = wq * 4 + p;
      const int cb = jt * 12;

      // prefetch this pass's gi chunks (latency hides under the k-loop)
      bf16x4 gpre[3][4];
      #pragma unroll
      for (int g = 0; g < 3; ++g)
        #pragma unroll
        for (int bt = 0; bt < 4; ++bt)
          gpre[g][bt] = gi[gibase + ((size_t)(cb + g * 4 + bt) << 6) + lane];

      f32x4 acc[3][4];
      #pragma unroll
      for (int g = 0; g < 3; ++g)
        #pragma unroll
        for (int bt = 0; bt < 4; ++bt) acc[g][bt] = (f32x4){0.f, 0.f, 0.f, 0.f};

      #pragma unroll 4
      for (int kk = 0; kk < 16; ++kk) {
        bf16x8 hf[4];
        #pragma unroll
        for (int bt = 0; bt < 4; ++bt)
          hf[bt] = *(const bf16x8*)(&cur[(bt * 16 + l15) * 1024 + ((kk * 64) ^ kbase)]);
        #pragma unroll
        for (int g = 0; g < 3; ++g) {
          bf16x8 wf = whh[((g * 32 + jt) * 16 + kk) * 64 + lane];
          #pragma unroll
          for (int bt = 0; bt < 4; ++bt)
            acc[g][bt] = __builtin_amdgcn_mfma_f32_16x16x32_bf16(wf, hf[bt], acc[g][bt], 0, 0, 0);
        }
      }
      // GRU cell epilogue: h_new ds_written straight into nxt (no reg hold,
      // no global round-trip).
      {
        int j = jt * 16 + lk * 4;
        f32x4 bn4 = *(const f32x4*)(b_hh + 1024 + j);
        #pragma unroll
        for (int bt = 0; bt < 4; ++bt) {
          f32x4 gr  = up4(gpre[0][bt]);
          f32x4 gz  = up4(gpre[1][bt]);
          f32x4 gn  = up4(gpre[2][bt]);
          f32x4 hov = up4(*(const bf16x4*)(&cur[(bt * 16 + l15) * 1024 +
                                                ((jt * 32) ^ cbase)]));
          f32x4 hv;
          #pragma unroll
          for (int r = 0; r < 4; ++r) {
            float rv = sigm(gr[r] + acc[0][bt][r]);
            float zv = sigm(gz[r] + acc[1][bt][r]);
            float nv = tanhf_(gn[r] + rv * (acc[2][bt][r] + bn4[r]));
            hv[r] = (1.0f - zv) * nv + zv * hov[r];
          }
          *(bf16x4*)(&nxt[(bt * 16 + l15) * 1024 + ((jt * 32) ^ cbase)]) = pk4(hv);
        }
      }
    }
    __syncthreads();   // h_{t+1} writes drained & visible; h_t reads all done

    { char* tmp = cur; cur = nxt; nxt = tmp; }   // cur = h_{t+1}

    // logits_t = h_{t+1} @ w_out^T + b_out ; waves 0..3 each own one btile.
    // Concurrent with other waves' next-step k-loop (both only READ cur;
    // their epilogue writes go to nxt — disjoint).
    if (wq < 4) {
      f32x4 lacc = (f32x4){0.f, 0.f, 0.f, 0.f};
      #pragma unroll 4
      for (int kk = 0; kk < 16; ++kk) {
        bf16x8 hf = *(const bf16x8*)(&cur[(wq * 16 + l15) * 1024 + ((kk * 64) ^ kbase)]);
        bf16x8 wf = wop[kk * 64 + lane];
        lacc = __builtin_amdgcn_mfma_f32_16x16x32_bf16(wf, hf, lacc, 0, 0, 0);
      }
      size_t ob = (size_t)(brow0 + wq * 16 + l15) * 60 + t * 10 + lk * 4;
      if (lk < 2) {
        f32x2 a = { lacc[0] + b_out[lk * 4 + 0], lacc[1] + b_out[lk * 4 + 1] };
        f32x2 b = { lacc[2] + b_out[lk * 4 + 2], lacc[3] + b_out[lk * 4 + 3] };
        *(f32x2*)(out + ob) = a;
        *(f32x2*)(out + ob + 2) = b;
      } else if (lk == 2) {
        f32x2 a = { lacc[0] + b_out[8], lacc[1] + b_out[9] };
        *(f32x2*)(out + ob) = a;
      }
    }
  }
}

extern "C" void kernel_launch(void* const* d_in, const int* in_sizes, int n_in,
                              void* d_out, int out_size, void* d_ws, size_t ws_size,
                              hipStream_t stream) {
  const float* x     = (const float*)d_in[0];
  const float* wih_f = (const float*)d_in[1];
  const float* whh_f = (const float*)d_in[2];
  const float* b_ih  = (const float*)d_in[3];
  const float* b_hh  = (const float*)d_in[4];
  const float* wout  = (const float*)d_in[5];
  const float* b_out = (const float*)d_in[6];

  char* ws = (char*)d_ws;
  bf16x8* wihPk = (bf16x8*)(ws + WIH_OFF);
  bf16x8* whhPk = (bf16x8*)(ws + WHH_OFF);
  bf16x8* wopPk = (bf16x8*)(ws + WOP_OFF);
  bf16x4* gi    = (bf16x4*)(ws + GI_OFF);

  prep_kernel<<<772, 256, 0, stream>>>(wih_f, whh_f, wout, wihPk, whhPk, wopPk);
  gru_kernel<<<NBLK, THREADS, 0, stream>>>(x, b_ih, b_hh, b_out,
                                           wihPk, whhPk, wopPk, gi, (float*)d_out);
}